// Round 4
// baseline (91.426 us; speedup 1.0000x reference)
//
#include <hip/hip_runtime.h>

#define BATCH 8
#define CH 256

typedef float f4_t __attribute__((ext_vector_type(4)));

// ---------------------------------------------------------------------------
// Fused kernel 1:
//  blocks [0,256):  per-pixel 256-ch dot on x0 (1x1 conv commutes with the
//                   4x4 avg pool) -> pooled m1,m2 [8,32,32].
//                   NEW: float4 pixel-quad loads, 4 channel-groups of 64,
//                   quad == horizontal pool extent (in-register h-pool).
//  blocks [256,512): two 3x3 convs (256ch->1) + relu on x2 -> c1,c2.
// 512 threads per block; branch is block-uniform.
// ---------------------------------------------------------------------------
__global__ __launch_bounds__(512)
void map_partial_kernel(const float* __restrict__ x0, const float* __restrict__ x2,
                        const float* __restrict__ cw0, const float* __restrict__ cb0,
                        const float* __restrict__ cw1, const float* __restrict__ cb1,
                        const float* __restrict__ ew0, const float* __restrict__ eb0,
                        const float* __restrict__ ew1, const float* __restrict__ eb1,
                        float* __restrict__ m1, float* __restrict__ m2,
                        float* __restrict__ c1, float* __restrict__ c2) {
    __shared__ f4_t sm1[4][128];   // 8 KB   (conv branch reuses as float[2048])
    __shared__ f4_t sm2[4][128];   // 8 KB
    int t = threadIdx.x;

    if (blockIdx.x < 256) {
        // ---- dot + 4x4 pool on x0 [8,256,128,128] -> m1,m2 [8,32,32] ----
        int blk = blockIdx.x;
        int b   = blk >> 5;        // batch
        int h   = blk & 31;        // pool row -> image rows 4h..4h+3
        int q   = t & 127;         // pixel-quad within the 4 rows (128 quads)
        int g   = t >> 7;          // channel group (4 groups x 64 ch)

        // f4 view: image is 4096 f4 per channel; rows 4h.. start at h*128 f4.
        const f4_t* xb = (const f4_t*)x0 + (size_t)b * (CH * 4096) + h * 128 + q;

        f4_t a1 = {0.f, 0.f, 0.f, 0.f};
        f4_t a2 = {0.f, 0.f, 0.f, 0.f};
#pragma unroll 16
        for (int ci = 0; ci < 64; ++ci) {
            int c = (g << 6) + ci;
            f4_t v = xb[(size_t)c * 4096];
            float W0 = cw0[c];
            float W1 = cw1[c];
            a1 += v * W0;
            a2 += v * W1;
        }
        sm1[g][q] = a1;
        sm2[g][q] = a2;
        __syncthreads();

        if (t < 32) {
            // pool cell (h, t): sum 4 rows x 4 groups, h-pool via component sum
            float t1 = 0.f, t2 = 0.f;
#pragma unroll
            for (int r = 0; r < 4; ++r)
#pragma unroll
                for (int gg = 0; gg < 4; ++gg) {
                    f4_t u = sm1[gg][r * 32 + t];
                    f4_t w = sm2[gg][r * 32 + t];
                    t1 += u.x + u.y + u.z + u.w;
                    t2 += w.x + w.y + w.z + w.w;
                }
            m1[b * 1024 + h * 32 + t] = fmaxf(t1 * 0.0625f + cb0[0], 0.f);
            m2[b * 1024 + h * 32 + t] = fmaxf(t2 * 0.0625f + cb1[0], 0.f);
        }
    } else {
        // ---- two 3x3 convs + relu on x2 [8,256,32,32] -> c1,c2 [8,32,32] ----
        float* s1 = (float*)sm1;
        float* s2 = (float*)sm2;
        int blk = blockIdx.x - 256;
        int y = blk & 31;
        int b = blk >> 5;
        int x  = t & 31;
        int cg = t >> 5;                      // 16 groups of 16 channels

        const float* xb = x2 + b * (CH * 1024);
        float a1 = 0.f, a2 = 0.f;

        for (int ci = 0; ci < 16; ++ci) {
            int c = cg * 16 + ci;
            const float* xc  = xb + c * 1024;
            const float* wc0 = ew0 + c * 9;
            const float* wc1 = ew1 + c * 9;
#pragma unroll
            for (int dy = -1; dy <= 1; ++dy) {
                int yy = y + dy;
                bool yok = (unsigned)yy < 32u;
#pragma unroll
                for (int dx = -1; dx <= 1; ++dx) {
                    int xx = x + dx;
                    bool ok = yok && ((unsigned)xx < 32u);
                    float v = ok ? xc[yy * 32 + xx] : 0.f;
                    int k = (dy + 1) * 3 + (dx + 1);
                    a1 += v * wc0[k];
                    a2 += v * wc1[k];
                }
            }
        }
        s1[t] = a1; s2[t] = a2;
        __syncthreads();

        if (t < 32) {
            float t1 = 0.f, t2 = 0.f;
#pragma unroll
            for (int g2 = 0; g2 < 16; ++g2) { t1 += s1[g2 * 32 + x]; t2 += s2[g2 * 32 + x]; }
            c1[b * 1024 + y * 32 + x] = fmaxf(t1 + eb0[0], 0.f);
            c2[b * 1024 + y * 32 + x] = fmaxf(t2 + eb1[0], 0.f);
        }
    }
}

// ---------------------------------------------------------------------------
// Kernel 2: per-batch means of m2/c2 (wave shuffle reduce), then
// tmap = m1*mean(m2) + c1*mean(c2).  8 blocks x 256 threads, float4.
// ---------------------------------------------------------------------------
__global__ __launch_bounds__(256)
void finalize_map_kernel(const float4* __restrict__ m1, const float4* __restrict__ m2,
                         const float4* __restrict__ c1, const float4* __restrict__ c2,
                         float4* __restrict__ tmap) {
    int b = blockIdx.x;
    int t = threadIdx.x;
    float4 v2 = m2[b * 256 + t];
    float4 w2 = c2[b * 256 + t];
    float sm = v2.x + v2.y + v2.z + v2.w;
    float sc = w2.x + w2.y + w2.z + w2.w;
#pragma unroll
    for (int off = 32; off > 0; off >>= 1) {
        sm += __shfl_down(sm, off);
        sc += __shfl_down(sc, off);
    }
    __shared__ float rm[4];
    __shared__ float rc[4];
    int wave = t >> 6, lane = t & 63;
    if (lane == 0) { rm[wave] = sm; rc[wave] = sc; }
    __syncthreads();
    float mm = (rm[0] + rm[1] + rm[2] + rm[3]) * (1.f / 1024.f);
    float mc = (rc[0] + rc[1] + rc[2] + rc[3]) * (1.f / 1024.f);

    float4 a1 = m1[b * 256 + t];
    float4 a2 = c1[b * 256 + t];
    float4 r;
    r.x = a1.x * mm + a2.x * mc;
    r.y = a1.y * mm + a2.y * mc;
    r.z = a1.z * mm + a2.z * mc;
    r.w = a1.w * mm + a2.w * mc;
    tmap[b * 256 + t] = r;
}

// ---------------------------------------------------------------------------
// Kernel 3: fused out = x + nearest_resize(tmap) for ALL five levels.
// 32 B per thread (2x float4); level boundaries are multiples of 512 so the
// level branch stays block-uniform. NT stores keep the output stream from
// evicting L3-resident inputs.
// ---------------------------------------------------------------------------
template<int LOG2S>
__device__ __forceinline__ int map_coord(int p) {
    if constexpr (LOG2S >= 5) return p >> (LOG2S - 5);
    else                      return p << (5 - LOG2S);
}

template<int S, int LOG2S>
__device__ __forceinline__ void add_level(const f4_t* __restrict__ x,
                                          f4_t* __restrict__ out,
                                          const float* __restrict__ tmap, int F) {
    constexpr int W4 = S / 4;
    int xq  = F & (W4 - 1);
    int row = F >> (LOG2S - 2);     // (b*256 + c)*S + y
    int y   = row & (S - 1);
    int b   = (row >> LOG2S) >> 8;  // C = 256

    int my = map_coord<LOG2S>(y);
    const float* mrow = tmap + b * 1024 + my * 32;

    int xp = xq * 4;
    f4_t v = x[F];
    f4_t r;
    r.x = v.x + mrow[map_coord<LOG2S>(xp + 0)];
    r.y = v.y + mrow[map_coord<LOG2S>(xp + 1)];
    r.z = v.z + mrow[map_coord<LOG2S>(xp + 2)];
    r.w = v.w + mrow[map_coord<LOG2S>(xp + 3)];
    __builtin_nontemporal_store(r, out + F);
}

__device__ __forceinline__ void add_dispatch(const f4_t* __restrict__ x0,
                                             const f4_t* __restrict__ x1,
                                             const f4_t* __restrict__ x2,
                                             const f4_t* __restrict__ x3,
                                             const f4_t* __restrict__ x4,
                                             f4_t* __restrict__ out,
                                             const float* __restrict__ tmap, int g);

// float4 level boundaries (all multiples of 512)
#define E0 8388608
#define E1 10485760
#define E2 11010048
#define E3 11141120
#define E4 11173888

__device__ __forceinline__ void add_dispatch(const f4_t* __restrict__ x0,
                                             const f4_t* __restrict__ x1,
                                             const f4_t* __restrict__ x2,
                                             const f4_t* __restrict__ x3,
                                             const f4_t* __restrict__ x4,
                                             f4_t* __restrict__ out,
                                             const float* __restrict__ tmap, int g) {
    if (g < E0)      add_level<128, 7>(x0, out,      tmap, g);
    else if (g < E1) add_level< 64, 6>(x1, out + E0, tmap, g - E0);
    else if (g < E2) add_level< 32, 5>(x2, out + E1, tmap, g - E1);
    else if (g < E3) add_level< 16, 4>(x3, out + E2, tmap, g - E2);
    else             add_level<  8, 3>(x4, out + E3, tmap, g - E3);
}

__global__ __launch_bounds__(256)
void add_all_kernel(const f4_t* __restrict__ x0, const f4_t* __restrict__ x1,
                    const f4_t* __restrict__ x2, const f4_t* __restrict__ x3,
                    const f4_t* __restrict__ x4, f4_t* __restrict__ out,
                    const float* __restrict__ tmap) {
    int base = blockIdx.x * 512;
    add_dispatch(x0, x1, x2, x3, x4, out, tmap, base + threadIdx.x);
    add_dispatch(x0, x1, x2, x3, x4, out, tmap, base + 256 + threadIdx.x);
}

// ---------------------------------------------------------------------------
extern "C" void kernel_launch(void* const* d_in, const int* in_sizes, int n_in,
                              void* d_out, int out_size, void* d_ws, size_t ws_size,
                              hipStream_t stream) {
    const float* x0 = (const float*)d_in[0];
    const float* x1 = (const float*)d_in[1];
    const float* x2 = (const float*)d_in[2];
    const float* x3 = (const float*)d_in[3];
    const float* x4 = (const float*)d_in[4];
    const float* com_w0 = (const float*)d_in[5];
    const float* com_b0 = (const float*)d_in[6];
    const float* com_w1 = (const float*)d_in[7];
    const float* com_b1 = (const float*)d_in[8];
    const float* en_w0  = (const float*)d_in[9];
    const float* en_b0  = (const float*)d_in[10];
    const float* en_w1  = (const float*)d_in[11];
    const float* en_b1  = (const float*)d_in[12];

    float* out = (float*)d_out;
    float* ws  = (float*)d_ws;
    float* m1   = ws;            // [8*1024] each
    float* m2   = ws + 8192;
    float* c1   = ws + 16384;
    float* c2   = ws + 24576;
    float* tmap = ws + 32768;

    map_partial_kernel<<<512, 512, 0, stream>>>(
        x0, x2, com_w0, com_b0, com_w1, com_b1,
        en_w0, en_b0, en_w1, en_b1, m1, m2, c1, c2);

    finalize_map_kernel<<<8, 256, 0, stream>>>(
        (const float4*)m1, (const float4*)m2,
        (const float4*)c1, (const float4*)c2, (float4*)tmap);

    add_all_kernel<<<E4 / 512, 256, 0, stream>>>(
        (const f4_t*)x0, (const f4_t*)x1, (const f4_t*)x2,
        (const f4_t*)x3, (const f4_t*)x4, (f4_t*)out, tmap);
}